// Round 1
// baseline (422.754 us; speedup 1.0000x reference)
//
#include <hip/hip_runtime.h>

typedef __bf16 bf16x8 __attribute__((ext_vector_type(8)));
typedef __bf16 bf16x4 __attribute__((ext_vector_type(4)));
typedef float  f32x4  __attribute__((ext_vector_type(4)));

// ---- workspace layout (in __bf16 elements) ----
constexpr int WS_AS0 = 0;        // A_static layer0: [64][64]
constexpr int WS_AS1 = 4096;     // A_static layer1
constexpr int WS_TH0 = 8192;     // th0 bf16 [128][256]
constexpr int WS_PH0 = 40960;
constexpr int WS_FC0 = 73728;    // fc0 bf16 [256][256]
constexpr int WS_TH1 = 139264;
constexpr int WS_PH1 = 172032;
constexpr int WS_FC1 = 204800;   // end at 270336 elems = 540672 B

static __device__ __forceinline__ f32x4 mfma16(bf16x8 a, bf16x8 b, f32x4 c) {
    return __builtin_amdgcn_mfma_f32_16x16x32_bf16(a, b, c, 0, 0, 0);
}

// ---------- prep: row-softmax of adj -> bf16 A_static ----------
__global__ void prep_adj(const float* __restrict__ adj0,
                         const float* __restrict__ adj1,
                         __bf16* __restrict__ wsb) {
    const int t = threadIdx.x;            // 128 threads: 2 layers x 64 rows
    const int l = t >> 6, r = t & 63;
    const float* a = (l ? adj1 : adj0) + r * 64;
    float mx = -3.0e38f;
    for (int c = 0; c < 64; ++c) mx = fmaxf(mx, a[c]);
    float s = 0.f;
    for (int c = 0; c < 64; ++c) s += __expf(a[c] - mx);
    const float inv = 1.f / s;
    __bf16* dst = wsb + (l ? WS_AS1 : WS_AS0) + r * 64;
    for (int c = 0; c < 64; ++c) dst[c] = (__bf16)(__expf(a[c] - mx) * inv);
}

// ---------- prep: f32 weights -> bf16 ----------
__global__ void prep_w(const float* __restrict__ th0, const float* __restrict__ ph0,
                       const float* __restrict__ fc0, const float* __restrict__ th1,
                       const float* __restrict__ ph1, const float* __restrict__ fc1,
                       __bf16* __restrict__ wsb) {
    int i = blockIdx.x * 256 + threadIdx.x;
    if (i >= 262144) return;
    float v; int d;
    if      (i <  32768) { v = th0[i];          d = WS_TH0 + i;          }
    else if (i <  65536) { v = ph0[i -  32768]; d = WS_PH0 + i -  32768; }
    else if (i < 131072) { v = fc0[i -  65536]; d = WS_FC0 + i -  65536; }
    else if (i < 163840) { v = th1[i - 131072]; d = WS_TH1 + i - 131072; }
    else if (i < 196608) { v = ph1[i - 163840]; d = WS_PH1 + i - 163840; }
    else                 { v = fc1[i - 196608]; d = WS_FC1 + i - 196608; }
    wsb[d] = (__bf16)v;
}

// ---------- fused 2-layer GCN: one block per batch element ----------
// 512 threads = 8 waves. LDS 78336 B -> 2 blocks/CU.
__global__ __launch_bounds__(512, 4) void fused_gcn(
    const float* __restrict__ graph,
    const float* __restrict__ ln_in_g, const float* __restrict__ ln_in_b,
    const __bf16* __restrict__ wsb,
    const float* __restrict__ fcb0, const float* __restrict__ ln0_g,
    const float* __restrict__ ln0_b, const float* __restrict__ fcb1,
    float* __restrict__ outp)
{
    constexpr int XN_S = 264;   // xn row stride (bf16), 528 B: 16B aligned, 2-way banks
    constexpr int QK_S = 136;   // q/k row stride, 272 B
    constexpr int ZT_S = 68;    // zT row stride, 136 B (8B aligned)
    constexpr int AH_S = 72;    // A_hat row stride, 144 B

    __shared__ __align__(16) __bf16 sXn[64 * XN_S];        // 33792 B
    __shared__ __align__(16) __bf16 sQKZ[2 * 64 * QK_S];   // 34816 B; q | k, overlaid by zT[256][68]
    __shared__ __align__(16) __bf16 sAh[64 * AH_S];        //  9216 B
    __shared__ float sRed[128];                            // row sums / sumsq

    const int tid = threadIdx.x;
    const int w = tid >> 6, lane = tid & 63;
    const int l15 = lane & 15, qd = lane >> 4;
    const int b = blockIdx.x;

    // ---- P1: LayerNorm(graph[b]) -> sXn (bf16). 8 threads per row.
    {
        const int r = tid >> 3, ci = (tid & 7) * 32;
        const float* gp = graph + (size_t)b * 16384 + r * 256 + ci;
        f32x4 v[8];
        float s = 0.f, s2 = 0.f;
        #pragma unroll
        for (int j = 0; j < 8; ++j) {
            v[j] = *(const f32x4*)(gp + j * 4);
            #pragma unroll
            for (int e = 0; e < 4; ++e) { s += v[j][e]; s2 += v[j][e] * v[j][e]; }
        }
        #pragma unroll
        for (int m = 1; m <= 4; m <<= 1) { s += __shfl_xor(s, m); s2 += __shfl_xor(s2, m); }
        const float mean = s * (1.f / 256.f);
        const float var  = s2 * (1.f / 256.f) - mean * mean;
        const float rstd = rsqrtf(var + 1e-5f);
        #pragma unroll
        for (int j = 0; j < 8; ++j) {
            f32x4 gg = *(const f32x4*)(ln_in_g + ci + j * 4);
            f32x4 bb = *(const f32x4*)(ln_in_b + ci + j * 4);
            bf16x4 pk;
            #pragma unroll
            for (int e = 0; e < 4; ++e)
                pk[e] = (__bf16)((v[j][e] - mean) * rstd * gg[e] + bb[e]);
            *(bf16x4*)&sXn[r * XN_S + ci + j * 4] = pk;
        }
    }
    __syncthreads();

    for (int layer = 0; layer < 2; ++layer) {
        const __bf16* As  = wsb + (layer ? WS_AS1 : WS_AS0);
        const __bf16* thb = wsb + (layer ? WS_TH1 : WS_TH0);
        const __bf16* phb = wsb + (layer ? WS_PH1 : WS_PH0);
        const __bf16* fcw = wsb + (layer ? WS_FC1 : WS_FC0);
        const float*  fcb = layer ? fcb1 : fcb0;

        // ---- P2: q = xn@th^T, k = xn@ph^T. wave w owns ntile w (16 cols of 128).
        {
            const int brow = w * 16 + l15;
            bf16x8 bth[8], bph[8];
            #pragma unroll
            for (int kk = 0; kk < 8; ++kk) {
                bth[kk] = *(const bf16x8*)(thb + brow * 256 + kk * 32 + qd * 8);
                bph[kk] = *(const bf16x8*)(phb + brow * 256 + kk * 32 + qd * 8);
            }
            #pragma unroll
            for (int m = 0; m < 4; ++m) {
                f32x4 aq = {0.f, 0.f, 0.f, 0.f}, ak = {0.f, 0.f, 0.f, 0.f};
                #pragma unroll
                for (int kk = 0; kk < 8; ++kk) {
                    bf16x8 a = *(const bf16x8*)&sXn[(m * 16 + l15) * XN_S + kk * 32 + qd * 8];
                    aq = mfma16(a, bth[kk], aq);
                    ak = mfma16(a, bph[kk], ak);
                }
                #pragma unroll
                for (int r = 0; r < 4; ++r) {
                    const int row = m * 16 + qd * 4 + r;
                    sQKZ[row * QK_S + w * 16 + l15]               = (__bf16)aq[r];
                    sQKZ[64 * QK_S + row * QK_S + w * 16 + l15]   = (__bf16)ak[r];
                }
            }
        }
        __syncthreads();

        // ---- P3: scores = q@k^T/sqrt(128) -> softmax -> +A_static -> sAh (waves 0-3)
        if (w < 4) {
            const int mb = w * 16;
            bf16x8 aq[4];
            #pragma unroll
            for (int kk = 0; kk < 4; ++kk)
                aq[kk] = *(const bf16x8*)&sQKZ[(mb + l15) * QK_S + kk * 32 + qd * 8];
            f32x4 sc[4];
            #pragma unroll
            for (int nt = 0; nt < 4; ++nt) {
                f32x4 acc = {0.f, 0.f, 0.f, 0.f};
                #pragma unroll
                for (int kk = 0; kk < 4; ++kk) {
                    bf16x8 bk = *(const bf16x8*)&sQKZ[64 * QK_S + (nt * 16 + l15) * QK_S + kk * 32 + qd * 8];
                    acc = mfma16(aq[kk], bk, acc);
                }
                sc[nt] = acc;
            }
            const float scale = 0.088388347648318447f; // 1/sqrt(128)
            #pragma unroll
            for (int r = 0; r < 4; ++r) {
                float v[4];
                #pragma unroll
                for (int nt = 0; nt < 4; ++nt) v[nt] = sc[nt][r] * scale;
                float mx = fmaxf(fmaxf(v[0], v[1]), fmaxf(v[2], v[3]));
                #pragma unroll
                for (int m = 1; m <= 8; m <<= 1) mx = fmaxf(mx, __shfl_xor(mx, m));
                float e[4], sum = 0.f;
                #pragma unroll
                for (int nt = 0; nt < 4; ++nt) { e[nt] = __expf(v[nt] - mx); sum += e[nt]; }
                #pragma unroll
                for (int m = 1; m <= 8; m <<= 1) sum += __shfl_xor(sum, m);
                const float inv = 1.f / sum;
                const int row = mb + qd * 4 + r;
                #pragma unroll
                for (int nt = 0; nt < 4; ++nt) {
                    const int col = nt * 16 + l15;
                    sAh[row * AH_S + col] = (__bf16)(e[nt] * inv + (float)As[row * 64 + col]);
                }
            }
        } else {
            const int i = tid - 256;
            if (i < 128) sRed[i] = 0.f;
        }
        __syncthreads();

        // ---- P4: z = xn@fc^T, stored transposed zT[o][m] over q/k region.
        {
            bf16x8 bfc[2][8];
            #pragma unroll
            for (int j = 0; j < 2; ++j) {
                const int o = (w * 2 + j) * 16 + l15;
                #pragma unroll
                for (int kk = 0; kk < 8; ++kk)
                    bfc[j][kk] = *(const bf16x8*)(fcw + o * 256 + kk * 32 + qd * 8);
            }
            #pragma unroll
            for (int m = 0; m < 4; ++m) {
                f32x4 az0 = {0.f, 0.f, 0.f, 0.f}, az1 = {0.f, 0.f, 0.f, 0.f};
                #pragma unroll
                for (int kk = 0; kk < 8; ++kk) {
                    bf16x8 a = *(const bf16x8*)&sXn[(m * 16 + l15) * XN_S + kk * 32 + qd * 8];
                    az0 = mfma16(a, bfc[0][kk], az0);
                    az1 = mfma16(a, bfc[1][kk], az1);
                }
                #pragma unroll
                for (int j = 0; j < 2; ++j) {
                    const f32x4 az = j ? az1 : az0;
                    const int o = (w * 2 + j) * 16 + l15;
                    bf16x4 pk;
                    #pragma unroll
                    for (int r = 0; r < 4; ++r) pk[r] = (__bf16)az[r];
                    // C-frag regs are 4 consecutive rows (m*16+qd*4+r) of one column o
                    *(bf16x4*)&sQKZ[o * ZT_S + m * 16 + qd * 4] = pk;
                }
            }
        }
        __syncthreads();

        // ---- P5: out = A_hat @ zT + fcb; fused LN(+leaky) epilogue or final store.
        {
            const int mb = (w & 3) * 16, ng = w >> 2;
            bf16x8 aa[2];
            #pragma unroll
            for (int kk = 0; kk < 2; ++kk)
                aa[kk] = *(const bf16x8*)&sAh[(mb + l15) * AH_S + kk * 32 + qd * 8];
            f32x4 oacc[8];
            #pragma unroll
            for (int j = 0; j < 8; ++j) {
                const int o = ng * 128 + j * 16 + l15;
                f32x4 acc = {0.f, 0.f, 0.f, 0.f};
                #pragma unroll
                for (int kk = 0; kk < 2; ++kk) {
                    bf16x4 lo = *(const bf16x4*)&sQKZ[o * ZT_S + kk * 32 + qd * 8];
                    bf16x4 hi = *(const bf16x4*)&sQKZ[o * ZT_S + kk * 32 + qd * 8 + 4];
                    bf16x8 bb = __builtin_shufflevector(lo, hi, 0, 1, 2, 3, 4, 5, 6, 7);
                    acc = mfma16(aa[kk], bb, acc);
                }
                const float bias = fcb[o];
                #pragma unroll
                for (int r = 0; r < 4; ++r) acc[r] += bias;
                oacc[j] = acc;
            }

            if (layer == 0) {
                // row stats (each row split across 16 lanes x 2 waves)
                #pragma unroll
                for (int r = 0; r < 4; ++r) {
                    float s = 0.f, s2 = 0.f;
                    #pragma unroll
                    for (int j = 0; j < 8; ++j) { const float vv = oacc[j][r]; s += vv; s2 += vv * vv; }
                    #pragma unroll
                    for (int m = 1; m <= 8; m <<= 1) { s += __shfl_xor(s, m); s2 += __shfl_xor(s2, m); }
                    if (l15 == 0) {
                        const int row = mb + qd * 4 + r;
                        atomicAdd(&sRed[row], s);
                        atomicAdd(&sRed[64 + row], s2);
                    }
                }
                __syncthreads();
                float mean4[4], rstd4[4];
                #pragma unroll
                for (int r = 0; r < 4; ++r) {
                    const int row = mb + qd * 4 + r;
                    const float mean = sRed[row] * (1.f / 256.f);
                    const float var  = sRed[64 + row] * (1.f / 256.f) - mean * mean;
                    mean4[r] = mean;
                    rstd4[r] = rsqrtf(var + 1e-5f);
                }
                #pragma unroll
                for (int j = 0; j < 8; ++j) {
                    const int o = ng * 128 + j * 16 + l15;
                    const float g = ln0_g[o], bb = ln0_b[o];
                    #pragma unroll
                    for (int r = 0; r < 4; ++r) {
                        float y = (oacc[j][r] - mean4[r]) * rstd4[r] * g + bb;
                        y = (y >= 0.f) ? y : 0.1f * y;   // LeakyReLU(0.1) after LN
                        sXn[(mb + qd * 4 + r) * XN_S + o] = (__bf16)y;
                    }
                }
                __syncthreads();
            } else {
                float* op = outp + (size_t)b * 16384;
                #pragma unroll
                for (int j = 0; j < 8; ++j) {
                    const int o = ng * 128 + j * 16 + l15;
                    #pragma unroll
                    for (int r = 0; r < 4; ++r)
                        op[(mb + qd * 4 + r) * 256 + o] = oacc[j][r];
                }
            }
        }
    }
}

extern "C" void kernel_launch(void* const* d_in, const int* in_sizes, int n_in,
                              void* d_out, int out_size, void* d_ws, size_t ws_size,
                              hipStream_t stream) {
    const float* graph   = (const float*)d_in[0];
    const float* ln_in_g = (const float*)d_in[1];
    const float* ln_in_b = (const float*)d_in[2];
    const float* adj0    = (const float*)d_in[3];
    const float* th0     = (const float*)d_in[4];
    const float* ph0     = (const float*)d_in[5];
    const float* fcw0    = (const float*)d_in[6];
    const float* fcb0    = (const float*)d_in[7];
    const float* ln0_g   = (const float*)d_in[8];
    const float* ln0_b   = (const float*)d_in[9];
    const float* adj1    = (const float*)d_in[10];
    const float* th1     = (const float*)d_in[11];
    const float* ph1     = (const float*)d_in[12];
    const float* fcw1    = (const float*)d_in[13];
    const float* fcb1    = (const float*)d_in[14];
    __bf16* wsb = (__bf16*)d_ws;

    prep_adj<<<1, 128, 0, stream>>>(adj0, adj1, wsb);
    prep_w<<<1024, 256, 0, stream>>>(th0, ph0, fcw0, th1, ph1, fcw1, wsb);
    fused_gcn<<<2048, 512, 0, stream>>>(graph, ln_in_g, ln_in_b, wsb,
                                        fcb0, ln0_g, ln0_b, fcb1, (float*)d_out);
}